// Round 15
// baseline (121.139 us; speedup 1.0000x reference)
//
#include <hip/hip_runtime.h>
#include <stdint.h>
#include <math.h>

#define S_LEN 2048
#define DIM   64
#define QBLK  128
#define KVBLK 64
#define NKV   (S_LEN / KVBLK)   // 32

typedef __attribute__((ext_vector_type(8))) short short8;
typedef __attribute__((ext_vector_type(4))) float f32x4;

// fp32 -> bf16 round-to-nearest-even (cold paths only)
static __device__ __forceinline__ unsigned short f2bf(float f) {
    union { float f; uint32_t u; } cv; cv.f = f;
    uint32_t u = cv.u;
    return (unsigned short)((u + 0x7fffu + ((u >> 16) & 1u)) >> 16);
}

// async global->LDS, 16B per lane, LDS dest = wave-uniform base + lane*16
static __device__ __forceinline__ void gload16(const void* g, void* l) {
    __builtin_amdgcn_global_load_lds(
        (const __attribute__((address_space(1))) unsigned int*)g,
        (__attribute__((address_space(3))) unsigned int*)l, 16, 0, 0);
}

static __device__ __forceinline__ float vmax3(float a, float b, float c) {
    float d;
    asm("v_max3_f32 %0, %1, %2, %3" : "=v"(d) : "v"(a), "v"(b), "v"(c));
    return d;
}

// ---------------- fused pre-kernel: K (blocks 0..4095) and V^T (blocks 4096..6143) ----------------
// K: chunk-XOR swizzle (R5-verified). V: [d][pos] kappa64-permuted, chunk-swizzled (R5-verified).
__global__ void cvt_kv(const float* __restrict__ kp, const float* __restrict__ vp,
                       unsigned short* __restrict__ kws, unsigned short* __restrict__ vtws) {
    const int tid = threadIdx.x;
    __shared__ unsigned short ldsT[DIM][72];   // used by V path only

    if (blockIdx.x < 4096) {   // ---- K path ----
        const int idx = blockIdx.x * 256 + tid;
        const int c   = idx & 7;
        const int s   = (idx >> 3) & (S_LEN - 1);
        const int bh  = idx >> 14;
        const float* src = kp + ((size_t)bh * S_LEN + s) * DIM + c * 8;
        const f32x4 a = *reinterpret_cast<const f32x4*>(src);
        const f32x4 b = *reinterpret_cast<const f32x4*>(src + 4);
        short8 t;
        t[0] = (short)f2bf(a[0]); t[1] = (short)f2bf(a[1]);
        t[2] = (short)f2bf(a[2]); t[3] = (short)f2bf(a[3]);
        t[4] = (short)f2bf(b[0]); t[5] = (short)f2bf(b[1]);
        t[6] = (short)f2bf(b[2]); t[7] = (short)f2bf(b[3]);
        unsigned short* dst = kws + ((size_t)bh * S_LEN + s) * DIM + (size_t)((c ^ (s & 7)) * 8);
        *reinterpret_cast<short8*>(dst) = t;
    } else {                   // ---- V path ----
        const int b  = blockIdx.x - 4096;
        const int bh = b >> 5;
        const int T  = b & 31;
        const int i = tid >> 2;
        const int dbase = (tid & 3) * 16;
        const float* src = vp + ((size_t)bh * S_LEN + T * 64 + i) * DIM + dbase;
#pragma unroll
        for (int q4 = 0; q4 < 4; ++q4) {
            const f32x4 a = *reinterpret_cast<const f32x4*>(src + q4 * 4);
#pragma unroll
            for (int j = 0; j < 4; ++j) ldsT[dbase + q4 * 4 + j][i] = f2bf(a[j]);
        }
        __syncthreads();
#pragma unroll
        for (int hh = 0; hh < 2; ++hh) {
            const int slot = tid + hh * 256;
            const int d = slot >> 3, c_st = slot & 7;
            const int cl = c_st ^ (d & 7);
            short8 t8;
#pragma unroll
            for (int j = 0; j < 8; ++j) {
                const int p = cl * 8 + j;
                const int kap = (p & 32) | ((p & 16) >> 1) | ((p & 8) >> 1) | ((p & 4) << 2) | (p & 3);
                t8[j] = (short)ldsT[d][kap];
            }
            unsigned short* dst = vtws + ((size_t)bh * DIM + d) * S_LEN + T * 64 + c_st * 8;
            *reinterpret_cast<short8*>(dst) = t8;
        }
    }
}

// -------- main attention (round-5 base, sequential, dbuf): C-seeded -m_run, shifted softmax --------
__global__ __launch_bounds__(256, 4)
void attn_fwd(const float* __restrict__ qp, const unsigned short* __restrict__ kws,
              const unsigned short* __restrict__ vtws, float* __restrict__ op) {
    const int lb = (blockIdx.x & 7) * 128 + (blockIdx.x >> 3);   // XCD swizzle (bijective)
    const int bh = lb >> 4;
    const int qb = lb & 15;
    const int tid  = threadIdx.x;
    const int wave = tid >> 6;
    const int lane = tid & 63;
    const int g = lane >> 4;
    const int r = lane & 15;

    __shared__ unsigned short klds[2][KVBLK * DIM];   // [key][chunk-swz] 8KB x2
    __shared__ unsigned short vlds[2][DIM * KVBLK];   // [d][pos-swz]     8KB x2

    const float*          qg    = qp   + (size_t)bh * (S_LEN * DIM);
    const unsigned short* kbase = kws  + (size_t)bh * (S_LEN * DIM);
    const unsigned short* vbase = vtws + (size_t)bh * (S_LEN * DIM);
    float*                og    = op   + (size_t)bh * (S_LEN * DIM);

    // Q frags (B-operand: col=q=lane&15, k=8g+i), pre-scaled by 0.125*log2(e) (base-2 scores)
    const float qscale = 0.125f * 1.44269504088896340736f;
    const int q0 = qb * QBLK + wave * 32;
    short8 qfrag[2][2];
#pragma unroll
    for (int mt = 0; mt < 2; ++mt) {
        const float* qrow = qg + (size_t)(q0 + mt * 16 + r) * DIM;
#pragma unroll
        for (int ks = 0; ks < 2; ++ks) {
            const f32x4 a = *reinterpret_cast<const f32x4*>(qrow + ks * 32 + 8 * g);
            const f32x4 b = *reinterpret_cast<const f32x4*>(qrow + ks * 32 + 8 * g + 4);
            short8 t;
            t[0] = (short)f2bf(a[0] * qscale); t[1] = (short)f2bf(a[1] * qscale);
            t[2] = (short)f2bf(a[2] * qscale); t[3] = (short)f2bf(a[3] * qscale);
            t[4] = (short)f2bf(b[0] * qscale); t[5] = (short)f2bf(b[1] * qscale);
            t[6] = (short)f2bf(b[2] * qscale); t[7] = (short)f2bf(b[3] * qscale);
            qfrag[mt][ks] = t;
        }
    }

    // O^T accumulators; m starts at 0 (scores emitted pre-shifted by -m, bounded by defer gate)
    f32x4 o[2][4];
    float m_run[2], l_part[2];
#pragma unroll
    for (int mt = 0; mt < 2; ++mt) {
#pragma unroll
        for (int nt = 0; nt < 4; ++nt) { f32x4 z = {0.f, 0.f, 0.f, 0.f}; o[mt][nt] = z; }
        m_run[mt] = 0.0f; l_part[mt] = 0.0f;
    }

    const int srow = lane >> 3, schk = lane & 7;
    auto stage = [&](int t, int buf) {
        const int kv0 = t * KVBLK;
#pragma unroll
        for (int h = 0; h < 2; ++h) {
            const int row = wave * 16 + h * 8;
            gload16(kbase + (size_t)(kv0 + row + srow) * DIM + schk * 8,
                    &klds[buf][row * DIM]);
            gload16(vbase + (size_t)(row + srow) * S_LEN + kv0 + schk * 8,
                    &vlds[buf][row * DIM]);
        }
    };

    // hoisted LDS fragment offsets (identical formula for klds and vlds)
    int off[4][2];
#pragma unroll
    for (int nt = 0; nt < 4; ++nt)
#pragma unroll
        for (int ks = 0; ks < 2; ++ks)
            off[nt][ks] = (nt * 16 + r) * DIM + (((ks << 2) | g) ^ (r & 7)) * 8;

    stage(0, 0);
    __syncthreads();
    int cur = 0;

    for (int t = 0; t < NKV; ++t) {
        if (t + 1 < NKV) stage(t + 1, cur ^ 1);   // prefetch; drains at end-of-iter barrier

        const unsigned short* kl = &klds[cur][0];
        const unsigned short* vl = &vlds[cur][0];

        // C-seed: scores come out of the MFMA already shifted by -m_run (per-lane q=r scalar)
        f32x4 ms0, ms1;
        ms0[0] = ms0[1] = ms0[2] = ms0[3] = -m_run[0];
        ms1[0] = ms1[1] = ms1[2] = ms1[3] = -m_run[1];

        // ---- S^T - m = K Q^T + (-m) : st[mt][nt][rg], key=nt*16+4g+rg, q=r ----
        f32x4 st[2][4];
        __builtin_amdgcn_s_setprio(1);
#pragma unroll
        for (int nt = 0; nt < 4; ++nt) {
            const short8 kf0 = *reinterpret_cast<const short8*>(kl + off[nt][0]);
            const short8 kf1 = *reinterpret_cast<const short8*>(kl + off[nt][1]);
            st[0][nt] = __builtin_amdgcn_mfma_f32_16x16x32_bf16(kf0, qfrag[0][0], ms0, 0, 0, 0);
            st[1][nt] = __builtin_amdgcn_mfma_f32_16x16x32_bf16(kf0, qfrag[1][0], ms1, 0, 0, 0);
            st[0][nt] = __builtin_amdgcn_mfma_f32_16x16x32_bf16(kf1, qfrag[0][1], st[0][nt], 0, 0, 0);
            st[1][nt] = __builtin_amdgcn_mfma_f32_16x16x32_bf16(kf1, qfrag[1][1], st[1][nt], 0, 0, 0);
        }
        __builtin_amdgcn_s_setprio(0);

        // ---- shifted-domain online softmax (defer gate: shifted max > 8) ----
#pragma unroll
        for (int mt = 0; mt < 2; ++mt) {
            const f32x4 s0 = st[mt][0], s1 = st[mt][1], s2 = st[mt][2], s3 = st[mt][3];
            const float a0 = vmax3(s0[0], s0[1], s0[2]);
            const float a1 = vmax3(s0[3], s1[0], s1[1]);
            const float a2 = vmax3(s1[2], s1[3], s2[0]);
            const float a3 = vmax3(s2[1], s2[2], s2[3]);
            const float a4 = vmax3(s3[0], s3[1], s3[2]);
            const float lane_mx = fmaxf(vmax3(a0, a1, a2), vmax3(a3, a4, s3[3]));
            f32x4 p[4];
            if (__any(lane_mx > 8.0f)) {
                float mx = fmaxf(lane_mx, __shfl_xor(lane_mx, 16));
                mx = fmaxf(mx, __shfl_xor(mx, 32));          // mx > 8 > 0: new max delta
                const float al = __builtin_amdgcn_exp2f(-mx);
                m_run[mt] += mx;
                l_part[mt] *= al;
#pragma unroll
                for (int nt = 0; nt < 4; ++nt) {
                    f32x4 sc = o[mt][nt];
                    sc[0] *= al; sc[1] *= al; sc[2] *= al; sc[3] *= al;
                    o[mt][nt] = sc;
                }
#pragma unroll
                for (int nt = 0; nt < 4; ++nt) {
                    p[nt][0] = __builtin_amdgcn_exp2f(st[mt][nt][0] - mx);
                    p[nt][1] = __builtin_amdgcn_exp2f(st[mt][nt][1] - mx);
                    p[nt][2] = __builtin_amdgcn_exp2f(st[mt][nt][2] - mx);
                    p[nt][3] = __builtin_amdgcn_exp2f(st[mt][nt][3] - mx);
                }
            } else {
#pragma unroll
                for (int nt = 0; nt < 4; ++nt) {             // common path: NO subtraction
                    p[nt][0] = __builtin_amdgcn_exp2f(st[mt][nt][0]);
                    p[nt][1] = __builtin_amdgcn_exp2f(st[mt][nt][1]);
                    p[nt][2] = __builtin_amdgcn_exp2f(st[mt][nt][2]);
                    p[nt][3] = __builtin_amdgcn_exp2f(st[mt][nt][3]);
                }
            }
            l_part[mt] += (((p[0][0] + p[0][1]) + (p[0][2] + p[0][3]))
                         + ((p[1][0] + p[1][1]) + (p[1][2] + p[1][3])))
                        + (((p[2][0] + p[2][1]) + (p[2][2] + p[2][3]))
                         + ((p[3][0] + p[3][1]) + (p[3][2] + p[3][3])));
            // pfrag[ks] slot i = P[key = 32ks+16(i>>2)+4g+(i&3)] = p[2ks+(i>>2)][i&3]
            short8 pfrag[2];
#pragma unroll
            for (int ks = 0; ks < 2; ++ks) {
                union { uint32_t u[4]; short8 v; } fr;
                asm("v_cvt_pk_bf16_f32 %0, %1, %2" : "=v"(fr.u[0]) : "v"(p[2*ks][0]),   "v"(p[2*ks][1]));
                asm("v_cvt_pk_bf16_f32 %0, %1, %2" : "=v"(fr.u[1]) : "v"(p[2*ks][2]),   "v"(p[2*ks][3]));
                asm("v_cvt_pk_bf16_f32 %0, %1, %2" : "=v"(fr.u[2]) : "v"(p[2*ks+1][0]), "v"(p[2*ks+1][1]));
                asm("v_cvt_pk_bf16_f32 %0, %1, %2" : "=v"(fr.u[3]) : "v"(p[2*ks+1][2]), "v"(p[2*ks+1][3]));
                pfrag[ks] = fr.v;
            }
            // ---- O^T[mt] += V^T P^T[mt] ----
            __builtin_amdgcn_s_setprio(1);
#pragma unroll
            for (int ntd = 0; ntd < 4; ++ntd) {
                const short8 vf0 = *reinterpret_cast<const short8*>(vl + off[ntd][0]);
                const short8 vf1 = *reinterpret_cast<const short8*>(vl + off[ntd][1]);
                o[mt][ntd] = __builtin_amdgcn_mfma_f32_16x16x32_bf16(vf0, pfrag[0], o[mt][ntd], 0, 0, 0);
                o[mt][ntd] = __builtin_amdgcn_mfma_f32_16x16x32_bf16(vf1, pfrag[1], o[mt][ntd], 0, 0, 0);
            }
            __builtin_amdgcn_s_setprio(0);
        }

        __syncthreads();
        cur ^= 1;
    }

    // ---- epilogue: l reduce over the 4 lane-groups, O^T/l, float4 stores ----
#pragma unroll
    for (int mt = 0; mt < 2; ++mt) {
        float lfull = l_part[mt];
        lfull += __shfl_xor(lfull, 16);
        lfull += __shfl_xor(lfull, 32);
        const float inv = 1.0f / lfull;
        float* dst = og + (size_t)(q0 + mt * 16 + r) * DIM + 4 * g;
#pragma unroll
        for (int ntd = 0; ntd < 4; ++ntd) {
            f32x4 tt = o[mt][ntd];
            tt[0] *= inv; tt[1] *= inv; tt[2] *= inv; tt[3] *= inv;
            *reinterpret_cast<f32x4*>(dst + ntd * 16) = tt;
        }
    }
}

extern "C" void kernel_launch(void* const* d_in, const int* in_sizes, int n_in,
                              void* d_out, int out_size, void* d_ws, size_t ws_size,
                              hipStream_t stream) {
    const float* q = (const float*)d_in[0];
    const float* k = (const float*)d_in[1];
    const float* v = (const float*)d_in[2];
    float* out = (float*)d_out;
    unsigned short* kws  = (unsigned short*)d_ws;
    unsigned short* vtws = kws + (size_t)64 * S_LEN * DIM;
    cvt_kv<<<dim3(6144), 256, 0, stream>>>(k, v, kws, vtws);
    attn_fwd<<<dim3(1024), 256, 0, stream>>>(q, kws, vtws, out);
}

// Round 16
// 105.137 us; speedup vs baseline: 1.1522x; 1.1522x over previous
//
#include <hip/hip_runtime.h>
#include <stdint.h>
#include <math.h>

#define S_LEN 2048
#define DIM   64
#define QBLK  128
#define KVBLK 32
#define NKV   (S_LEN / KVBLK)   // 64

typedef __attribute__((ext_vector_type(8))) short short8;
typedef __attribute__((ext_vector_type(4))) float f32x4;

// fp32 -> bf16 round-to-nearest-even (cold paths only)
static __device__ __forceinline__ unsigned short f2bf(float f) {
    union { float f; uint32_t u; } cv; cv.f = f;
    uint32_t u = cv.u;
    return (unsigned short)((u + 0x7fffu + ((u >> 16) & 1u)) >> 16);
}

// async global->LDS, 16B per lane, LDS dest = wave-uniform base + lane*16
static __device__ __forceinline__ void gload16(const void* g, void* l) {
    __builtin_amdgcn_global_load_lds(
        (const __attribute__((address_space(1))) unsigned int*)g,
        (__attribute__((address_space(3))) unsigned int*)l, 16, 0, 0);
}

static __device__ __forceinline__ float vmax3(float a, float b, float c) {
    float d;
    asm("v_max3_f32 %0, %1, %2, %3" : "=v"(d) : "v"(a), "v"(b), "v"(c));
    return d;
}

// ---------------- fused pre-kernel: K (blocks 0..4095) + V^T kappa32 (blocks 4096..6143) ----------------
// K: chunk-XOR swizzle (R5-verified). V: [d][key] in 32-key halves, kappa32 in-half, chunk-swizzled
// within 4-chunk halves (Round-11-verified layout — matches attn_fwd's stage/voff below).
__global__ void cvt_kv(const float* __restrict__ kp, const float* __restrict__ vp,
                       unsigned short* __restrict__ kws, unsigned short* __restrict__ vtws) {
    const int tid = threadIdx.x;
    __shared__ unsigned short ldsT[DIM][72];   // used by V path only

    if (blockIdx.x < 4096) {   // ---- K path ----
        const int idx = blockIdx.x * 256 + tid;
        const int c   = idx & 7;
        const int s   = (idx >> 3) & (S_LEN - 1);
        const int bh  = idx >> 14;
        const float* src = kp + ((size_t)bh * S_LEN + s) * DIM + c * 8;
        const f32x4 a = *reinterpret_cast<const f32x4*>(src);
        const f32x4 b = *reinterpret_cast<const f32x4*>(src + 4);
        short8 t;
        t[0] = (short)f2bf(a[0]); t[1] = (short)f2bf(a[1]);
        t[2] = (short)f2bf(a[2]); t[3] = (short)f2bf(a[3]);
        t[4] = (short)f2bf(b[0]); t[5] = (short)f2bf(b[1]);
        t[6] = (short)f2bf(b[2]); t[7] = (short)f2bf(b[3]);
        unsigned short* dst = kws + ((size_t)bh * S_LEN + s) * DIM + (size_t)((c ^ (s & 7)) * 8);
        *reinterpret_cast<short8*>(dst) = t;
    } else {                   // ---- V path (kappa32 halves) ----
        const int b  = blockIdx.x - 4096;
        const int bh = b >> 5;
        const int T  = b & 31;
        const int i = tid >> 2;
        const int dbase = (tid & 3) * 16;
        const float* src = vp + ((size_t)bh * S_LEN + T * 64 + i) * DIM + dbase;
#pragma unroll
        for (int q4 = 0; q4 < 4; ++q4) {
            const f32x4 a = *reinterpret_cast<const f32x4*>(src + q4 * 4);
#pragma unroll
            for (int j = 0; j < 4; ++j) ldsT[dbase + q4 * 4 + j][i] = f2bf(a[j]);
        }
        __syncthreads();
#pragma unroll
        for (int hh = 0; hh < 2; ++hh) {
            const int slot = tid + hh * 256;          // 0..511 = (d, h, c_st)
            const int d = slot >> 3;
            const int h = (slot >> 2) & 1;
            const int c_st = slot & 3;
            const int cl = c_st ^ ((d >> 1) & 3);
            short8 t8;
#pragma unroll
            for (int j = 0; j < 8; ++j) {
                const int p = cl * 8 + j;
                const int kap = ((p & 4) << 2) | ((p & 16) >> 1) | ((p & 8) >> 1) | (p & 3);
                t8[j] = (short)ldsT[d][h * 32 + kap];
            }
            unsigned short* dst = vtws + ((size_t)bh * DIM + d) * S_LEN + T * 64 + h * 32 + c_st * 8;
            *reinterpret_cast<short8*>(dst) = t8;
        }
    }
}

// ---- pipeline phases as macros on directly-named locals (SROA-safe) ----
#define QK_TILE(ST, KL)                                                                               \
    do {                                                                                              \
        __builtin_amdgcn_s_setprio(1);                                                                \
        _Pragma("unroll")                                                                             \
        for (int nt = 0; nt < 2; ++nt) {                                                              \
            const short8 kf0 = *reinterpret_cast<const short8*>((KL) + koff[nt][0]);                  \
            const short8 kf1 = *reinterpret_cast<const short8*>((KL) + koff[nt][1]);                  \
            ST[0][nt] = __builtin_amdgcn_mfma_f32_16x16x32_bf16(kf0, qfrag[0][0], z4, 0, 0, 0);       \
            ST[1][nt] = __builtin_amdgcn_mfma_f32_16x16x32_bf16(kf0, qfrag[1][0], z4, 0, 0, 0);       \
            ST[0][nt] = __builtin_amdgcn_mfma_f32_16x16x32_bf16(kf1, qfrag[0][1], ST[0][nt], 0, 0, 0);\
            ST[1][nt] = __builtin_amdgcn_mfma_f32_16x16x32_bf16(kf1, qfrag[1][1], ST[1][nt], 0, 0, 0);\
        }                                                                                             \
        __builtin_amdgcn_s_setprio(0);                                                                \
    } while (0)

#define SMPV(ST, VL)                                                                                  \
    do {                                                                                              \
        short8 pfA, pfB;                                                                              \
        _Pragma("unroll")                                                                             \
        for (int mt = 0; mt < 2; ++mt) {                                                              \
            const f32x4 s0 = ST[mt][0], s1 = ST[mt][1];                                               \
            const float a0 = vmax3(s0[0], s0[1], s0[2]);                                              \
            const float a1 = vmax3(s0[3], s1[0], s1[1]);                                              \
            const float lane_mx = vmax3(a0, a1, fmaxf(s1[2], s1[3]));                                 \
            if (__any(lane_mx > m_run[mt] + 8.0f)) {                                                  \
                float mx = fmaxf(lane_mx, __shfl_xor(lane_mx, 16));                                   \
                mx = fmaxf(mx, __shfl_xor(mx, 32));                                                   \
                const float mnew = fmaxf(m_run[mt], mx);                                              \
                const float al = __builtin_amdgcn_exp2f(m_run[mt] - mnew);                            \
                m_run[mt] = mnew;                                                                     \
                l_part[mt] *= al;                                                                     \
                _Pragma("unroll")                                                                     \
                for (int nt = 0; nt < 4; ++nt) {                                                      \
                    f32x4 sc = o[mt][nt];                                                             \
                    sc[0] *= al; sc[1] *= al; sc[2] *= al; sc[3] *= al;                               \
                    o[mt][nt] = sc;                                                                   \
                }                                                                                     \
            }                                                                                         \
            const float mnow = m_run[mt];                                                             \
            f32x4 p0, p1;                                                                             \
            p0[0] = __builtin_amdgcn_exp2f(ST[mt][0][0] - mnow);                                      \
            p0[1] = __builtin_amdgcn_exp2f(ST[mt][0][1] - mnow);                                      \
            p0[2] = __builtin_amdgcn_exp2f(ST[mt][0][2] - mnow);                                      \
            p0[3] = __builtin_amdgcn_exp2f(ST[mt][0][3] - mnow);                                      \
            p1[0] = __builtin_amdgcn_exp2f(ST[mt][1][0] - mnow);                                      \
            p1[1] = __builtin_amdgcn_exp2f(ST[mt][1][1] - mnow);                                      \
            p1[2] = __builtin_amdgcn_exp2f(ST[mt][1][2] - mnow);                                      \
            p1[3] = __builtin_amdgcn_exp2f(ST[mt][1][3] - mnow);                                      \
            l_part[mt] += ((p0[0] + p0[1]) + (p0[2] + p0[3])) + ((p1[0] + p1[1]) + (p1[2] + p1[3])); \
            union { uint32_t u[4]; short8 v; } fr;                                                    \
            asm("v_cvt_pk_bf16_f32 %0, %1, %2" : "=v"(fr.u[0]) : "v"(p0[0]), "v"(p0[1]));             \
            asm("v_cvt_pk_bf16_f32 %0, %1, %2" : "=v"(fr.u[1]) : "v"(p0[2]), "v"(p0[3]));             \
            asm("v_cvt_pk_bf16_f32 %0, %1, %2" : "=v"(fr.u[2]) : "v"(p1[0]), "v"(p1[1]));             \
            asm("v_cvt_pk_bf16_f32 %0, %1, %2" : "=v"(fr.u[3]) : "v"(p1[2]), "v"(p1[3]));             \
            if (mt == 0) pfA = fr.v; else pfB = fr.v;                                                 \
        }                                                                                             \
        __builtin_amdgcn_s_setprio(1);                                                                \
        _Pragma("unroll")                                                                             \
        for (int ntd = 0; ntd < 4; ++ntd) {                                                           \
            const short8 vf = *reinterpret_cast<const short8*>((VL) + voff[ntd]);                     \
            o[0][ntd] = __builtin_amdgcn_mfma_f32_16x16x32_bf16(vf, pfA, o[0][ntd], 0, 0, 0);         \
            o[1][ntd] = __builtin_amdgcn_mfma_f32_16x16x32_bf16(vf, pfB, o[1][ntd], 0, 0, 0);         \
        }                                                                                             \
        __builtin_amdgcn_s_setprio(0);                                                                \
    } while (0)

// -------- main attention (Round-13 verbatim): QBLK=128, KVBLK=32, QK(t) || SMPV(t-1) --------
__global__ __launch_bounds__(256, 4)
void attn_fwd(const float* __restrict__ qp, const unsigned short* __restrict__ kws,
              const unsigned short* __restrict__ vtws, float* __restrict__ op) {
    const int lb = (blockIdx.x & 7) * 128 + (blockIdx.x >> 3);   // XCD swizzle (bijective, 1024)
    const int bh = lb >> 4;
    const int qb = lb & 15;
    const int tid  = threadIdx.x;
    const int wave = tid >> 6;
    const int lane = tid & 63;
    const int g = lane >> 4;
    const int r = lane & 15;

    __shared__ unsigned short klds[2][KVBLK * DIM];   // 2 x 4KB, linear (gload16)
    __shared__ unsigned short vlds[2][DIM * 32];      // 2 x 4KB, 64B rows (gload16)

    const float*          qg    = qp   + (size_t)bh * (S_LEN * DIM);
    const unsigned short* kbase = kws  + (size_t)bh * (S_LEN * DIM);
    const unsigned short* vbase = vtws + (size_t)bh * (S_LEN * DIM);
    float*                og    = op   + (size_t)bh * (S_LEN * DIM);

    // Q frags (B-operand: col=q, k=8g+i), pre-scaled by 0.125*log2(e) (base-2 scores)
    const float qscale = 0.125f * 1.44269504088896340736f;
    const int q0 = qb * QBLK + wave * 32;
    short8 qfrag[2][2];
#pragma unroll
    for (int mt = 0; mt < 2; ++mt) {
        const float* qrow = qg + (size_t)(q0 + mt * 16 + r) * DIM;
#pragma unroll
        for (int ks = 0; ks < 2; ++ks) {
            const f32x4 a = *reinterpret_cast<const f32x4*>(qrow + ks * 32 + 8 * g);
            const f32x4 b = *reinterpret_cast<const f32x4*>(qrow + ks * 32 + 8 * g + 4);
            short8 t;
            t[0] = (short)f2bf(a[0] * qscale); t[1] = (short)f2bf(a[1] * qscale);
            t[2] = (short)f2bf(a[2] * qscale); t[3] = (short)f2bf(a[3] * qscale);
            t[4] = (short)f2bf(b[0] * qscale); t[5] = (short)f2bf(b[1] * qscale);
            t[6] = (short)f2bf(b[2] * qscale); t[7] = (short)f2bf(b[3] * qscale);
            qfrag[mt][ks] = t;
        }
    }

    // O^T accumulators + lane-uniform m,l per mt
    f32x4 o[2][4];
    float m_run[2], l_part[2];
#pragma unroll
    for (int mt = 0; mt < 2; ++mt) {
#pragma unroll
        for (int nt = 0; nt < 4; ++nt) { f32x4 z = {0.f, 0.f, 0.f, 0.f}; o[mt][nt] = z; }
        m_run[mt] = -INFINITY; l_part[mt] = 0.0f;
    }

    // staging (Round-11-verified addressing): K 1 gload16/wave; V 1 gload16/wave (kappa32 halves)
    const int srow = lane >> 3, schk = lane & 7;
    const int vd = wave * 16 + ((lane >> 2) & 15), vcst = lane & 3;
    auto stageK = [&](int t, int buf) {
        gload16(kbase + (size_t)(t * KVBLK + wave * 8 + srow) * DIM + schk * 8,
                &klds[buf][(wave * 8) * DIM]);
    };
    auto stageV = [&](int t, int buf) {
        gload16(vbase + (size_t)vd * S_LEN + (t >> 1) * 64 + (t & 1) * 32 + vcst * 8,
                &vlds[buf][wave * 512]);
    };

    // hoisted LDS read offsets (Round-11-verified)
    int koff[2][2], voff[4];
#pragma unroll
    for (int nt = 0; nt < 2; ++nt)
#pragma unroll
        for (int ks = 0; ks < 2; ++ks)
            koff[nt][ks] = (nt * 16 + r) * DIM + (((ks << 2) | g) ^ (r & 7)) * 8;
#pragma unroll
    for (int nt = 0; nt < 4; ++nt)
        voff[nt] = (nt * 16 + r) * 32 + (g ^ ((r >> 1) & 3)) * 8;

    const f32x4 z4 = {0.f, 0.f, 0.f, 0.f};
    const unsigned short* kl0 = &klds[0][0];
    const unsigned short* kl1 = &klds[1][0];
    const unsigned short* vl0 = &vlds[0][0];
    const unsigned short* vl1 = &vlds[1][0];

    // score double-state (even tiles -> stA, odd -> stB)
    f32x4 stA[2][2], stB[2][2];

    // ---- prologue ----
    stageK(0, 0);
    __syncthreads();
    // t = 0
    stageK(1, 1); stageV(0, 0);
    QK_TILE(stA, kl0);
    __syncthreads();
    // t = 1
    stageK(2, 0); stageV(1, 1);
    QK_TILE(stB, kl1);
    SMPV(stA, vl0);
    __syncthreads();

    // ---- main loop, 2-unrolled: QK(t) || SMPV(t-1) ----
    for (int tt = 2; tt < NKV; tt += 2) {
        // t = tt (even): K(t) in klds[0]; V(t-1) in vlds[1]
        stageK(tt + 1, 1);
        stageV(tt, 0);
        QK_TILE(stA, kl0);
        SMPV(stB, vl1);
        __syncthreads();
        // t = tt+1 (odd): K(t) in klds[1]; V(t-1) in vlds[0]
        if (tt + 2 < NKV) stageK(tt + 2, 0);
        stageV(tt + 1, 1);
        QK_TILE(stB, kl1);
        SMPV(stA, vl0);
        __syncthreads();
    }
    // ---- epilogue: last tile (NKV-1, odd) ----
    SMPV(stB, vl1);

#pragma unroll
    for (int mt = 0; mt < 2; ++mt) {
        float lfull = l_part[mt];
        lfull += __shfl_xor(lfull, 16);
        lfull += __shfl_xor(lfull, 32);
        const float inv = 1.0f / lfull;
        float* dst = og + (size_t)(q0 + mt * 16 + r) * DIM + 4 * g;
#pragma unroll
        for (int ntd = 0; ntd < 4; ++ntd) {
            f32x4 tt = o[mt][ntd];
            tt[0] *= inv; tt[1] *= inv; tt[2] *= inv; tt[3] *= inv;
            *reinterpret_cast<f32x4*>(dst + ntd * 16) = tt;
        }
    }
}

extern "C" void kernel_launch(void* const* d_in, const int* in_sizes, int n_in,
                              void* d_out, int out_size, void* d_ws, size_t ws_size,
                              hipStream_t stream) {
    const float* q = (const float*)d_in[0];
    const float* k = (const float*)d_in[1];
    const float* v = (const float*)d_in[2];
    float* out = (float*)d_out;
    unsigned short* kws  = (unsigned short*)d_ws;
    unsigned short* vtws = kws + (size_t)64 * S_LEN * DIM;
    cvt_kv<<<dim3(6144), 256, 0, stream>>>(k, v, kws, vtws);
    attn_fwd<<<dim3(1024), 256, 0, stream>>>(q, kws, vtws, out);
}